// Round 10
// baseline (138.760 us; speedup 1.0000x reference)
//
#include <hip/hip_runtime.h>

// ---------------------------------------------------------------------------
// SPP_CNN: conv1d(128->128,K=21,VALID) + BN(eval) + LeakyReLU(0.01)
//          + 2x ragged SPP-max (levels 1,2) + FC(768->2)
// R10 = R9 with k_conv re-decomposed: waves = 4 t-quarters x FULL 128co
// (was 2co x 2t). Kills the wr-pair bv duplication -> LDS b128 traffic
// halves (16 -> 8 per wave-tap); av rotation keeps the proven 60-MFMA
// prefetch-use distance; W L2 traffic unchanged (1.41 GB).
// Pipeline: 4 dispatches (absmax -> fused prep -> conv -> fc).
// Workspace layout:
//   Xt   : i8  [32][8192][128]  (x transposed, quantized)     @ 0
//   Wp   : i8  [21][2][8][64][16] ([k][wr][f=ks*4+m][lane][e])@ 33554432
//   bnA  : f32 [128] (gamma*inv/(sx*sw))                      @ 33898496
//   bnB  : f32 [128]                                          @ 33899008
//   feat : u32 [32][768]  (monotonic float keys)              @ 33899520
//   parts: f32 [1344]     (absmax per-wave partials)          @ 33997824
// ---------------------------------------------------------------------------

typedef __attribute__((ext_vector_type(4))) float f32x4;
typedef __attribute__((ext_vector_type(4))) int i32x4;
typedef unsigned short u16;
typedef unsigned int u32;
typedef signed char i8;

#define T_SZ 8192
#define C_SZ 128
#define B_SZ 32
#define KW 21
#define FEAT 768
#define SX 25.4f              /* 127/5: x ~ N(0,1), clip at 5 sigma */
#define IMIN (-2147483647 - 1)

#define XT_OFF  0
#define WP_OFF  33554432u
#define BNA_OFF 33898496u
#define BNB_OFF 33899008u
#define FK_OFF  33899520u
#define PT_OFF  33997824u

__device__ __forceinline__ u32 fkey(float f) {          // order-preserving
  u32 u = __float_as_uint(f);
  return (u & 0x80000000u) ? ~u : (u | 0x80000000u);
}
__device__ __forceinline__ float funkey(u32 k) {
  u32 u = (k & 0x80000000u) ? (k ^ 0x80000000u) : ~k;
  return __uint_as_float(u);
}

__device__ __forceinline__ i8 q8(float v) {
  v = fminf(fmaxf(v, -127.f), 127.f);
  return (i8)__float2int_rn(v);
}

__device__ __forceinline__ void gload_lds16(void* lds, const void* g) {
  __builtin_amdgcn_global_load_lds(
      (const __attribute__((address_space(1))) u32*)g,
      (__attribute__((address_space(3))) u32*)lds, 16, 0, 0);
}

// --------------------------- prep: |W| absmax partials ---------------------
__global__ void k_absmax(const float* __restrict__ W, float* __restrict__ parts) {
  const int i0 = ((int)blockIdx.x * 256 + (int)threadIdx.x) * 4;  // 336 blocks
  float m = 0.f;
#pragma unroll
  for (int j = 0; j < 4; ++j) m = fmaxf(m, fabsf(W[i0 + j]));
#pragma unroll
  for (int d = 1; d < 64; d <<= 1) m = fmaxf(m, __shfl_xor(m, d));
  if ((threadIdx.x & 63) == 0)
    parts[blockIdx.x * 4 + (threadIdx.x >> 6)] = m;
}

// --------------------------- fused prep ------------------------------------
// 256 threads; block-wide max of parts[1344] (used by bn & w paths).
__device__ __forceinline__ float reduce_parts(const float* __restrict__ parts,
                                              float* lds4) {
  float m = 0.f;
  for (int i = (int)threadIdx.x; i < 1344; i += 256) m = fmaxf(m, parts[i]);
#pragma unroll
  for (int d = 1; d < 64; d <<= 1) m = fmaxf(m, __shfl_xor(m, d));
  if (((int)threadIdx.x & 63) == 0) lds4[(int)threadIdx.x >> 6] = m;
  __syncthreads();
  return fmaxf(fmaxf(lds4[0], lds4[1]), fmaxf(lds4[2], lds4[3]));
}

__global__ void k_fused(const float* __restrict__ X, const float* __restrict__ W,
                        const float* __restrict__ g, const float* __restrict__ be,
                        const float* __restrict__ mn, const float* __restrict__ vr,
                        const float* __restrict__ parts,
                        i8* __restrict__ Xt, i8* __restrict__ Wp,
                        float* __restrict__ bnA, float* __restrict__ bnB,
                        u32* __restrict__ feat) {
  __shared__ float smem[C_SZ * 65];           // xt tile / reduce scratch
  const int tid = (int)threadIdx.x;
  const int bid = (int)blockIdx.x;

  if (bid < 4096) {
    // ---- X -> i8 transposed [b][t][ci], fixed scale SX ----
    const int b = bid >> 7;
    const int t0 = (bid & 127) * 64;
    const float* Xb = X + (size_t)b * C_SZ * T_SZ;
    {
      const int cw = tid >> 4;                // 0..15
      const int ch = tid & 15;                // float4 chunk along t
#pragma unroll
      for (int it = 0; it < 8; ++it) {
        const int ci = it * 16 + cw;
        const f32x4 v = *(const f32x4*)&Xb[(size_t)ci * T_SZ + t0 + ch * 4];
        smem[ci * 65 + ch * 4 + 0] = v.x;
        smem[ci * 65 + ch * 4 + 1] = v.y;
        smem[ci * 65 + ch * 4 + 2] = v.z;
        smem[ci * 65 + ch * 4 + 3] = v.w;
      }
    }
    __syncthreads();
    const int t = tid >> 2;                   // 0..63
    const int q = tid & 3;                    // 32-ci quarter
    u32 dw[8];
#pragma unroll
    for (int d = 0; d < 8; ++d) {
      u32 w = 0;
#pragma unroll
      for (int jb = 0; jb < 4; ++jb) {
        const int j = d * 4 + jb;
        const float v = smem[(q * 32 + j) * 65 + t] * SX;
        w |= ((u32)(unsigned char)q8(v)) << (jb * 8);
      }
      dw[d] = w;
    }
    u32* dst = (u32*)(Xt + ((size_t)(b * T_SZ + t0 + t)) * C_SZ + q * 32);
    *(i32x4*)(dst + 0) = (i32x4){(int)dw[0], (int)dw[1], (int)dw[2], (int)dw[3]};
    *(i32x4*)(dst + 4) = (i32x4){(int)dw[4], (int)dw[5], (int)dw[6], (int)dw[7]};
  } else if (bid == 4096) {
    // ---- BN fold (+ dequant scale) and feat zeroing ----
    const float wmax = reduce_parts(parts, smem);
    if (tid < C_SZ) {
      const float sw = 127.f / wmax;
      const float invS = 1.f / (SX * sw);
      float inv = rsqrtf(vr[tid] + 1e-5f);
      float a = g[tid] * inv;
      bnA[tid] = a * invS;
      bnB[tid] = be[tid] - a * mn[tid];
    }
    for (int i = tid; i < B_SZ * FEAT; i += 256) feat[i] = 0u;
  } else {
    // ---- W -> i8 wave panels ----
    // Wp byte idx = (((k*2+wr)*8 + f)*64 + lane)*16 + e   (f = ks*4 + m)
    // maps W[co = wr*64+m*16+(lane&15)][ci = ks*64+(lane>>4)*16+e][k]
    const float wmax = reduce_parts(parts, smem);
    const float sw = 127.f / wmax;
    const int i = (bid - 4097) * 256 + tid;   // 1344 blocks -> 344064
    const int e = i & 15;
    const int lane = (i >> 4) & 63;
    const int f = (i >> 10) & 7;
    const int wr = (i >> 13) & 1;
    const int k = i >> 14;
    const int m = f & 3, ks = f >> 2;
    const int co = wr * 64 + m * 16 + (lane & 15);
    const int ci = ks * 64 + (lane >> 4) * 16 + e;
    Wp[i] = q8(W[(co * C_SZ + ci) * KW + k] * sw);
  }
}

// --------------------------- conv + SPP-max (int domain) -------------------
// Block 256 thr = 4 waves, wave wc = t-quarter (64 t) x FULL 128 co.
// Per tap per wave: 8 bv b128 (zero duplication in block), 64 MFMA,
// av[2][8] register panels rotated per-m (prefetch-use distance = 60 MFMA).
// bv from granule-XOR swizzled i8 Xs (row = 128B = 8 granules, XOR row&7).
// Epilogue: window max in raw i32 (BN+leaky monotone, bnA>0); 4 windows
// reduced, w0/w3 derived at combine.
__global__ __launch_bounds__(256, 2)
void k_conv(const i8* __restrict__ Xt, const i8* __restrict__ Wp,
            const float* __restrict__ bnA, const float* __restrict__ bnB,
            const int* __restrict__ olen, u32* __restrict__ feat) {
  __shared__ __align__(16) i8 Xs[280 * C_SZ];   // 35840 B
  __shared__ int parti[4][4][C_SZ];             //  8192 B (total 44032)

  const int tid = (int)threadIdx.x;
  const int wc = tid >> 6, lane = tid & 63;
  const int l4 = lane & 15, lh = lane >> 4;
  const int b = (int)blockIdx.y;
  const int t0 = (int)blockIdx.x * 256;

  // ---- prefetch W panels for tap 0 ----
  // av[ks][m] byte offset: (m>>2)*8192 + (ks*4 + (m&3))*1024 + lane*16
  i32x4 av[2][8];
  {
    const i8* wb = Wp + (lane << 4);
#pragma unroll
    for (int ks = 0; ks < 2; ++ks)
#pragma unroll
      for (int m = 0; m < 8; ++m)
        av[ks][m] = *(const i32x4*)&wb[((m >> 2) << 13) + (((ks << 2) + (m & 3)) << 10)];
  }

  // ---- stage Xs rows 0..279 (8 rows = 1024B per wave-instruction) ----
  // LDS[row][g] = global[row][g ^ (row&7)] (16B granules)
  {
    const i8* xb = Xt + (size_t)b * T_SZ * C_SZ;
    for (int i = wc; i < 35; i += 4) {
      int trow = t0 + i * 8 + (lane >> 3);
      trow = trow < T_SZ ? trow : (T_SZ - 1);
      const i8* src = xb + (size_t)trow * C_SZ + (((lane & 7) ^ (trow & 7)) << 4);
      gload_lds16(&Xs[i * 1024], src);
    }
  }
  __syncthreads();                            // the only barrier before epilogue

  i32x4 acc[8][4];
#pragma unroll
  for (int m = 0; m < 8; ++m)
#pragma unroll
    for (int n = 0; n < 4; ++n) acc[m][n] = (i32x4){0, 0, 0, 0};

  const int rowc = wc * 64 + l4;
#pragma unroll 3
  for (int k = 0; k < KW; ++k) {
    const int kn = (k + 1 < KW) ? (k + 1) : k;
    const int rowb = rowc + k;
    const i8* wbn = Wp + ((size_t)kn << 14) + (lane << 4);
#pragma unroll
    for (int ks = 0; ks < 2; ++ks) {
      const int gran = ((ks << 2) + lh) ^ (rowb & 7);
      const i8* xp = &Xs[(rowb << 7) + (gran << 4)];
      i32x4 bv[4];
#pragma unroll
      for (int n = 0; n < 4; ++n)
        bv[n] = *(const i32x4*)&xp[n << 11];  // n*16 rows * 128B
      __builtin_amdgcn_s_setprio(1);
#pragma unroll
      for (int m = 0; m < 8; ++m) {
#pragma unroll
        for (int n = 0; n < 4; ++n)
          acc[m][n] = __builtin_amdgcn_mfma_i32_16x16x64_i8(
              av[ks][m], bv[n], acc[m][n], 0, 0, 0);
        // prefetch av[ks][m] for next tap (constant 60-MFMA distance)
        av[ks][m] = *(const i32x4*)&wbn[((m >> 2) << 13) +
                                        (((ks << 2) + (m & 3)) << 10)];
      }
      __builtin_amdgcn_s_setprio(0);
    }
  }

  // ---- epilogue: 4-window ragged max in i32 domain ----
  const int len = olen[b];
  const int L1 = len - (KW - 1);
  const int L2 = len - 2 * (KW - 1);
  int wlo[4], whi[4];
  wlo[0] = 0;       whi[0] = (L1 + 1) >> 1;   // w1
  wlo[1] = L1 >> 1; whi[1] = L1;              // w2
  wlo[2] = 0;       whi[2] = (L2 + 1) >> 1;   // w4
  wlo[3] = L2 >> 1; whi[3] = L2;              // w5

  int tg[4];
#pragma unroll
  for (int n = 0; n < 4; ++n) tg[n] = t0 + wc * 64 + n * 16 + l4;

#pragma unroll
  for (int w = 0; w < 4; ++w) {
    bool pr[4];
#pragma unroll
    for (int n = 0; n < 4; ++n) pr[n] = (tg[n] >= wlo[w]) & (tg[n] < whi[w]);
#pragma unroll
    for (int m = 0; m < 8; ++m)
#pragma unroll
      for (int r = 0; r < 4; ++r) {
        int mx = IMIN;
#pragma unroll
        for (int n = 0; n < 4; ++n)
          mx = max(mx, pr[n] ? acc[m][n][r] : IMIN);
#pragma unroll
        for (int d = 1; d < 16; d <<= 1) mx = max(mx, __shfl_xor(mx, d));
        if (l4 == 0) parti[wc][w][m * 16 + lh * 4 + r] = mx;
      }
  }
  __syncthreads();
  // ---- combine: BN + leaky + fkey on 6x128 reduced values ----
  if (tid < C_SZ) {
    const int c = tid;
    const int v1 = max(max(parti[0][0][c], parti[1][0][c]),
                       max(parti[2][0][c], parti[3][0][c]));
    const int v2 = max(max(parti[0][1][c], parti[1][1][c]),
                       max(parti[2][1][c], parti[3][1][c]));
    const int v4 = max(max(parti[0][2][c], parti[1][2][c]),
                       max(parti[2][2][c], parti[3][2][c]));
    const int v5 = max(max(parti[0][3][c], parti[1][3][c]),
                       max(parti[2][3][c], parti[3][3][c]));
    const int v0 = max(v1, v2);
    const int v3 = max(v4, v5);
    const float a = bnA[c], bb = bnB[c];
    u32* fb_ = feat + b * FEAT;
    float h;
    h = a * (float)v0 + bb; h = h > 0.f ? h : 0.01f * h;
    atomicMax(&fb_[c], fkey(h));
    h = a * (float)v1 + bb; h = h > 0.f ? h : 0.01f * h;
    atomicMax(&fb_[128 + 2 * c], fkey(h));
    h = a * (float)v2 + bb; h = h > 0.f ? h : 0.01f * h;
    atomicMax(&fb_[129 + 2 * c], fkey(h));
    h = a * (float)v3 + bb; h = h > 0.f ? h : 0.01f * h;
    atomicMax(&fb_[384 + c], fkey(h));
    h = a * (float)v4 + bb; h = h > 0.f ? h : 0.01f * h;
    atomicMax(&fb_[512 + 2 * c], fkey(h));
    h = a * (float)v5 + bb; h = h > 0.f ? h : 0.01f * h;
    atomicMax(&fb_[513 + 2 * c], fkey(h));
  }
}

// --------------------------- FC head ---------------------------------------
__global__ void k_fc(const u32* __restrict__ feat, const float* __restrict__ fw,
                     const float* __restrict__ fb, float* __restrict__ out) {
  const int bj = (int)blockIdx.x;             // 0..63
  const int b = bj >> 1, j = bj & 1;
  const int lane = (int)threadIdx.x;          // 64
  float s = 0.f;
  for (int i = lane; i < FEAT; i += 64)
    s += funkey(feat[b * FEAT + i]) * fw[j * FEAT + i];
#pragma unroll
  for (int d = 1; d < 64; d <<= 1) s += __shfl_xor(s, d);
  if (lane == 0) out[b * 2 + j] = s + fb[j];
}

// ---------------------------------------------------------------------------
extern "C" void kernel_launch(void* const* d_in, const int* in_sizes, int n_in,
                              void* d_out, int out_size, void* d_ws, size_t ws_size,
                              hipStream_t stream) {
  (void)in_sizes; (void)n_in; (void)out_size; (void)ws_size;
  const float* x     = (const float*)d_in[0];
  const int*   olen  = (const int*)d_in[1];
  const float* w     = (const float*)d_in[2];
  const float* gamma = (const float*)d_in[3];
  const float* beta  = (const float*)d_in[4];
  const float* mean  = (const float*)d_in[5];
  const float* var   = (const float*)d_in[6];
  const float* fw    = (const float*)d_in[7];
  const float* fb    = (const float*)d_in[8];
  float* out = (float*)d_out;

  char* ws = (char*)d_ws;
  i8*  Xt    = (i8*)(ws + XT_OFF);
  i8*  Wp    = (i8*)(ws + WP_OFF);
  float* bnA  = (float*)(ws + BNA_OFF);
  float* bnB  = (float*)(ws + BNB_OFF);
  u32* feat  = (u32*)(ws + FK_OFF);
  float* parts = (float*)(ws + PT_OFF);

  k_absmax<<<336, 256, 0, stream>>>(w, parts);
  k_fused<<<4097 + 1344, 256, 0, stream>>>(x, w, gamma, beta, mean, var, parts,
                                           Xt, Wp, bnA, bnB, feat);
  k_conv<<<dim3(T_SZ / 256, B_SZ), 256, 0, stream>>>(Xt, Wp, bnA, bnB, olen, feat);
  k_fc<<<64, 64, 0, stream>>>(feat, fw, fb, out);
}

// Round 11
// 119.329 us; speedup vs baseline: 1.1628x; 1.1628x over previous
//
#include <hip/hip_runtime.h>

// ---------------------------------------------------------------------------
// SPP_CNN: conv1d(128->128,K=21,VALID) + BN(eval) + LeakyReLU(0.01)
//          + 2x ragged SPP-max (levels 1,2) + FC(768->2)
// R11 = R9 with k_conv's 21-tap loop FULLY unrolled: compile-time Wp
// addresses (kills VALU addr chains), straight-line body lets the scheduler
// hoist next-tap loads into MFMA bursts within the 256-reg budget.
// Invariant (R3/R8/R10 lessons): wave = 64co x 128t, av 8KB/tap/wave,
// 64 MFMA/tap prefetch distance. Do not reshape.
// Pipeline: 4 dispatches (absmax -> fused prep -> conv -> fc).
// Workspace layout:
//   Xt   : i8  [32][8192][128]  (x transposed, quantized)     @ 0
//   Wp   : i8  [21][2][8][64][16] ([k][wr][f=ks*4+m][lane][e])@ 33554432
//   bnA  : f32 [128] (gamma*inv/(sx*sw))                      @ 33898496
//   bnB  : f32 [128]                                          @ 33899008
//   feat : u32 [32][768]  (monotonic float keys)              @ 33899520
//   parts: f32 [1344]     (absmax per-wave partials)          @ 33997824
// ---------------------------------------------------------------------------

typedef __attribute__((ext_vector_type(4))) float f32x4;
typedef __attribute__((ext_vector_type(4))) int i32x4;
typedef unsigned short u16;
typedef unsigned int u32;
typedef signed char i8;

#define T_SZ 8192
#define C_SZ 128
#define B_SZ 32
#define KW 21
#define FEAT 768
#define SX 25.4f              /* 127/5: x ~ N(0,1), clip at 5 sigma */
#define IMIN (-2147483647 - 1)

#define XT_OFF  0
#define WP_OFF  33554432u
#define BNA_OFF 33898496u
#define BNB_OFF 33899008u
#define FK_OFF  33899520u
#define PT_OFF  33997824u

__device__ __forceinline__ u32 fkey(float f) {          // order-preserving
  u32 u = __float_as_uint(f);
  return (u & 0x80000000u) ? ~u : (u | 0x80000000u);
}
__device__ __forceinline__ float funkey(u32 k) {
  u32 u = (k & 0x80000000u) ? (k ^ 0x80000000u) : ~k;
  return __uint_as_float(u);
}

__device__ __forceinline__ i8 q8(float v) {
  v = fminf(fmaxf(v, -127.f), 127.f);
  return (i8)__float2int_rn(v);
}

__device__ __forceinline__ void gload_lds16(void* lds, const void* g) {
  __builtin_amdgcn_global_load_lds(
      (const __attribute__((address_space(1))) u32*)g,
      (__attribute__((address_space(3))) u32*)lds, 16, 0, 0);
}

// --------------------------- prep: |W| absmax partials ---------------------
__global__ void k_absmax(const float* __restrict__ W, float* __restrict__ parts) {
  const int i0 = ((int)blockIdx.x * 256 + (int)threadIdx.x) * 4;  // 336 blocks
  float m = 0.f;
#pragma unroll
  for (int j = 0; j < 4; ++j) m = fmaxf(m, fabsf(W[i0 + j]));
#pragma unroll
  for (int d = 1; d < 64; d <<= 1) m = fmaxf(m, __shfl_xor(m, d));
  if ((threadIdx.x & 63) == 0)
    parts[blockIdx.x * 4 + (threadIdx.x >> 6)] = m;
}

// --------------------------- fused prep ------------------------------------
// 256 threads; block-wide max of parts[1344] (used by bn & w paths).
__device__ __forceinline__ float reduce_parts(const float* __restrict__ parts,
                                              float* lds4) {
  float m = 0.f;
  for (int i = (int)threadIdx.x; i < 1344; i += 256) m = fmaxf(m, parts[i]);
#pragma unroll
  for (int d = 1; d < 64; d <<= 1) m = fmaxf(m, __shfl_xor(m, d));
  if (((int)threadIdx.x & 63) == 0) lds4[(int)threadIdx.x >> 6] = m;
  __syncthreads();
  return fmaxf(fmaxf(lds4[0], lds4[1]), fmaxf(lds4[2], lds4[3]));
}

__global__ void k_fused(const float* __restrict__ X, const float* __restrict__ W,
                        const float* __restrict__ g, const float* __restrict__ be,
                        const float* __restrict__ mn, const float* __restrict__ vr,
                        const float* __restrict__ parts,
                        i8* __restrict__ Xt, i8* __restrict__ Wp,
                        float* __restrict__ bnA, float* __restrict__ bnB,
                        u32* __restrict__ feat) {
  __shared__ float smem[C_SZ * 65];           // xt tile / reduce scratch
  const int tid = (int)threadIdx.x;
  const int bid = (int)blockIdx.x;

  if (bid < 4096) {
    // ---- X -> i8 transposed [b][t][ci], fixed scale SX ----
    const int b = bid >> 7;
    const int t0 = (bid & 127) * 64;
    const float* Xb = X + (size_t)b * C_SZ * T_SZ;
    {
      const int cw = tid >> 4;                // 0..15
      const int ch = tid & 15;                // float4 chunk along t
#pragma unroll
      for (int it = 0; it < 8; ++it) {
        const int ci = it * 16 + cw;
        const f32x4 v = *(const f32x4*)&Xb[(size_t)ci * T_SZ + t0 + ch * 4];
        smem[ci * 65 + ch * 4 + 0] = v.x;
        smem[ci * 65 + ch * 4 + 1] = v.y;
        smem[ci * 65 + ch * 4 + 2] = v.z;
        smem[ci * 65 + ch * 4 + 3] = v.w;
      }
    }
    __syncthreads();
    const int t = tid >> 2;                   // 0..63
    const int q = tid & 3;                    // 32-ci quarter
    u32 dw[8];
#pragma unroll
    for (int d = 0; d < 8; ++d) {
      u32 w = 0;
#pragma unroll
      for (int jb = 0; jb < 4; ++jb) {
        const int j = d * 4 + jb;
        const float v = smem[(q * 32 + j) * 65 + t] * SX;
        w |= ((u32)(unsigned char)q8(v)) << (jb * 8);
      }
      dw[d] = w;
    }
    u32* dst = (u32*)(Xt + ((size_t)(b * T_SZ + t0 + t)) * C_SZ + q * 32);
    *(i32x4*)(dst + 0) = (i32x4){(int)dw[0], (int)dw[1], (int)dw[2], (int)dw[3]};
    *(i32x4*)(dst + 4) = (i32x4){(int)dw[4], (int)dw[5], (int)dw[6], (int)dw[7]};
  } else if (bid == 4096) {
    // ---- BN fold (+ dequant scale) and feat zeroing ----
    const float wmax = reduce_parts(parts, smem);
    if (tid < C_SZ) {
      const float sw = 127.f / wmax;
      const float invS = 1.f / (SX * sw);
      float inv = rsqrtf(vr[tid] + 1e-5f);
      float a = g[tid] * inv;
      bnA[tid] = a * invS;
      bnB[tid] = be[tid] - a * mn[tid];
    }
    for (int i = tid; i < B_SZ * FEAT; i += 256) feat[i] = 0u;
  } else {
    // ---- W -> i8 wave panels ----
    // Wp byte idx = (((k*2+wr)*8 + f)*64 + lane)*16 + e   (f = ks*4 + m)
    // maps W[co = wr*64+m*16+(lane&15)][ci = ks*64+(lane>>4)*16+e][k]
    const float wmax = reduce_parts(parts, smem);
    const float sw = 127.f / wmax;
    const int i = (bid - 4097) * 256 + tid;   // 1344 blocks -> 344064
    const int e = i & 15;
    const int lane = (i >> 4) & 63;
    const int f = (i >> 10) & 7;
    const int wr = (i >> 13) & 1;
    const int k = i >> 14;
    const int m = f & 3, ks = f >> 2;
    const int co = wr * 64 + m * 16 + (lane & 15);
    const int ci = ks * 64 + (lane >> 4) * 16 + e;
    Wp[i] = q8(W[(co * C_SZ + ci) * KW + k] * sw);
  }
}

// --------------------------- conv + SPP-max (int domain) -------------------
// Block 256 thr (4 waves 2x2), tile 128co x 256t; wave 64co x 128t.
// FULLY-unrolled barrier-free K-loop; av in registers (L2 panels, ks-half
// rotation; prefetch-to-use distance 64 MFMA — do not shrink); bv from
// granule-XOR swizzled i8 Xs (row = 128B = 8 granules). Epilogue: window
// max in raw i32 (BN+leaky monotone, bnA>0); 4 windows reduced, 2 derived.
__global__ __launch_bounds__(256, 2)
void k_conv(const i8* __restrict__ Xt, const i8* __restrict__ Wp,
            const float* __restrict__ bnA, const float* __restrict__ bnB,
            const int* __restrict__ olen, u32* __restrict__ feat) {
  __shared__ __align__(16) i8 Xs[280 * C_SZ];   // 35840 B
  __shared__ int parti[2][4][C_SZ];             //  4096 B (total 39936)

  const int tid = (int)threadIdx.x;
  const int wid = tid >> 6, lane = tid & 63;
  const int wr = wid >> 1, wc = wid & 1;
  const int l4 = lane & 15, lh = lane >> 4;
  const int b = (int)blockIdx.y;
  const int t0 = (int)blockIdx.x * 256;

  // ---- prefetch W panels for tap 0 ----
  const i8* wbase = Wp + ((size_t)wr << 13) + (lane << 4);
  i32x4 av[2][4];
#pragma unroll
  for (int f = 0; f < 8; ++f)
    av[f >> 2][f & 3] = *(const i32x4*)&wbase[f << 10];

  // ---- stage Xs rows 0..279 (8 rows = 1024B per wave-instruction) ----
  // LDS[row][g] = global[row][g ^ (row&7)] (16B granules)
  {
    const i8* xb = Xt + (size_t)b * T_SZ * C_SZ;
    for (int i = wid; i < 35; i += 4) {
      int trow = t0 + i * 8 + (lane >> 3);
      trow = trow < T_SZ ? trow : (T_SZ - 1);
      const i8* src = xb + (size_t)trow * C_SZ + (((lane & 7) ^ (trow & 7)) << 4);
      gload_lds16(&Xs[i * 1024], src);
    }
  }
  __syncthreads();                            // the only barrier before epilogue

  i32x4 acc[4][8];
#pragma unroll
  for (int m = 0; m < 4; ++m)
#pragma unroll
    for (int n = 0; n < 8; ++n) acc[m][n] = (i32x4){0, 0, 0, 0};

  const int rowc = wc * 128 + l4;
#pragma unroll
  for (int k = 0; k < KW; ++k) {              // FULL unroll: static Wp offsets
    const int kn = (k + 1 < KW) ? (k + 1) : k;
    const int rowb = rowc + k;
    const i8* wbn = wbase + ((size_t)kn << 14);
#pragma unroll
    for (int ks = 0; ks < 2; ++ks) {
      const int gran = ((ks << 2) + lh) ^ (rowb & 7);
      const i8* xp = &Xs[(rowb << 7) + (gran << 4)];
      i32x4 bv[8];
#pragma unroll
      for (int n = 0; n < 8; ++n)
        bv[n] = *(const i32x4*)&xp[n << 11];  // n*16 rows * 128B
      __builtin_amdgcn_s_setprio(1);
#pragma unroll
      for (int m = 0; m < 4; ++m)
#pragma unroll
        for (int n = 0; n < 8; ++n)
          acc[m][n] = __builtin_amdgcn_mfma_i32_16x16x64_i8(
              av[ks][m], bv[n], acc[m][n], 0, 0, 0);
      __builtin_amdgcn_s_setprio(0);
      // prefetch this ks-half of next tap (distance ~32 MFMA min)
#pragma unroll
      for (int m = 0; m < 4; ++m)
        av[ks][m] = *(const i32x4*)&wbn[((ks << 2) + m) << 10];
    }
  }

  // ---- epilogue: 4-window ragged max in i32 domain ----
  const int len = olen[b];
  const int L1 = len - (KW - 1);
  const int L2 = len - 2 * (KW - 1);
  int wlo[4], whi[4];
  wlo[0] = 0;       whi[0] = (L1 + 1) >> 1;   // w1
  wlo[1] = L1 >> 1; whi[1] = L1;              // w2
  wlo[2] = 0;       whi[2] = (L2 + 1) >> 1;   // w4
  wlo[3] = L2 >> 1; whi[3] = L2;              // w5

  int tg[8];
#pragma unroll
  for (int n = 0; n < 8; ++n) tg[n] = t0 + wc * 128 + n * 16 + l4;

#pragma unroll
  for (int w = 0; w < 4; ++w) {
    bool pr[8];
#pragma unroll
    for (int n = 0; n < 8; ++n) pr[n] = (tg[n] >= wlo[w]) & (tg[n] < whi[w]);
#pragma unroll
    for (int m = 0; m < 4; ++m)
#pragma unroll
      for (int r = 0; r < 4; ++r) {
        int mx = IMIN;
#pragma unroll
        for (int n = 0; n < 8; ++n)
          mx = max(mx, pr[n] ? acc[m][n][r] : IMIN);
#pragma unroll
        for (int d = 1; d < 16; d <<= 1) mx = max(mx, __shfl_xor(mx, d));
        if (l4 == 0) parti[wc][w][wr * 64 + m * 16 + lh * 4 + r] = mx;
      }
  }
  __syncthreads();
  // ---- combine: BN + leaky + fkey on 6x128 reduced values ----
  if (tid < C_SZ) {
    const int c = tid;
    const int v1 = max(parti[0][0][c], parti[1][0][c]);
    const int v2 = max(parti[0][1][c], parti[1][1][c]);
    const int v4 = max(parti[0][2][c], parti[1][2][c]);
    const int v5 = max(parti[0][3][c], parti[1][3][c]);
    const int v0 = max(v1, v2);
    const int v3 = max(v4, v5);
    const float a = bnA[c], bb = bnB[c];
    u32* fb_ = feat + b * FEAT;
    float h;
    h = a * (float)v0 + bb; h = h > 0.f ? h : 0.01f * h;
    atomicMax(&fb_[c], fkey(h));
    h = a * (float)v1 + bb; h = h > 0.f ? h : 0.01f * h;
    atomicMax(&fb_[128 + 2 * c], fkey(h));
    h = a * (float)v2 + bb; h = h > 0.f ? h : 0.01f * h;
    atomicMax(&fb_[129 + 2 * c], fkey(h));
    h = a * (float)v3 + bb; h = h > 0.f ? h : 0.01f * h;
    atomicMax(&fb_[384 + c], fkey(h));
    h = a * (float)v4 + bb; h = h > 0.f ? h : 0.01f * h;
    atomicMax(&fb_[512 + 2 * c], fkey(h));
    h = a * (float)v5 + bb; h = h > 0.f ? h : 0.01f * h;
    atomicMax(&fb_[513 + 2 * c], fkey(h));
  }
}

// --------------------------- FC head ---------------------------------------
__global__ void k_fc(const u32* __restrict__ feat, const float* __restrict__ fw,
                     const float* __restrict__ fb, float* __restrict__ out) {
  const int bj = (int)blockIdx.x;             // 0..63
  const int b = bj >> 1, j = bj & 1;
  const int lane = (int)threadIdx.x;          // 64
  float s = 0.f;
  for (int i = lane; i < FEAT; i += 64)
    s += funkey(feat[b * FEAT + i]) * fw[j * FEAT + i];
#pragma unroll
  for (int d = 1; d < 64; d <<= 1) s += __shfl_xor(s, d);
  if (lane == 0) out[b * 2 + j] = s + fb[j];
}

// ---------------------------------------------------------------------------
extern "C" void kernel_launch(void* const* d_in, const int* in_sizes, int n_in,
                              void* d_out, int out_size, void* d_ws, size_t ws_size,
                              hipStream_t stream) {
  (void)in_sizes; (void)n_in; (void)out_size; (void)ws_size;
  const float* x     = (const float*)d_in[0];
  const int*   olen  = (const int*)d_in[1];
  const float* w     = (const float*)d_in[2];
  const float* gamma = (const float*)d_in[3];
  const float* beta  = (const float*)d_in[4];
  const float* mean  = (const float*)d_in[5];
  const float* var   = (const float*)d_in[6];
  const float* fw    = (const float*)d_in[7];
  const float* fb    = (const float*)d_in[8];
  float* out = (float*)d_out;

  char* ws = (char*)d_ws;
  i8*  Xt    = (i8*)(ws + XT_OFF);
  i8*  Wp    = (i8*)(ws + WP_OFF);
  float* bnA  = (float*)(ws + BNA_OFF);
  float* bnB  = (float*)(ws + BNB_OFF);
  u32* feat  = (u32*)(ws + FK_OFF);
  float* parts = (float*)(ws + PT_OFF);

  k_absmax<<<336, 256, 0, stream>>>(w, parts);
  k_fused<<<4097 + 1344, 256, 0, stream>>>(x, w, gamma, beta, mean, var, parts,
                                           Xt, Wp, bnA, bnB, feat);
  k_conv<<<dim3(T_SZ / 256, B_SZ), 256, 0, stream>>>(Xt, Wp, bnA, bnB, olen, feat);
  k_fc<<<64, 64, 0, stream>>>(feat, fw, fb, out);
}

// Round 12
// 104.288 us; speedup vs baseline: 1.3305x; 1.1442x over previous
//
#include <hip/hip_runtime.h>

// ---------------------------------------------------------------------------
// SPP_CNN: conv1d(128->128,K=21,VALID) + BN(eval) + LeakyReLU(0.01)
//          + 2x ragged SPP-max (levels 1,2) + FC(768->2)
// R12 = R11 + ragged early-exit: all SPP windows live in [0, L1(b)),
// L1 = orig_len-20, mean ~4590 of 8192 -> ~44% of conv outputs are dead.
//  - k_conv: block exits if t0 >= L1(b) (uniform, before any load).
//  - k_fused xt path: skip 64-row tiles with t0 > L1(b)+278 (max row any
//    surviving conv block stages is t0+279 <= L1+278; T_SZ clamp only
//    fires for exited blocks). Skipped Xt rows are stale but never read.
// k_conv inner structure = R11 exact (int8 MFMA, fully-unrolled barrier-free
// K-loop, register av, i32-domain monotone epilogue). Invariant: wave =
// 64co x 128t, av 8KB/tap/wave, 64-MFMA prefetch distance. Do not reshape.
// Workspace layout:
//   Xt   : i8  [32][8192][128]  (x transposed, quantized)     @ 0
//   Wp   : i8  [21][2][8][64][16] ([k][wr][f=ks*4+m][lane][e])@ 33554432
//   bnA  : f32 [128] (gamma*inv/(sx*sw))                      @ 33898496
//   bnB  : f32 [128]                                          @ 33899008
//   feat : u32 [32][768]  (monotonic float keys)              @ 33899520
//   parts: f32 [1344]     (absmax per-wave partials)          @ 33997824
// ---------------------------------------------------------------------------

typedef __attribute__((ext_vector_type(4))) float f32x4;
typedef __attribute__((ext_vector_type(4))) int i32x4;
typedef unsigned short u16;
typedef unsigned int u32;
typedef signed char i8;

#define T_SZ 8192
#define C_SZ 128
#define B_SZ 32
#define KW 21
#define FEAT 768
#define SX 25.4f              /* 127/5: x ~ N(0,1), clip at 5 sigma */
#define IMIN (-2147483647 - 1)

#define XT_OFF  0
#define WP_OFF  33554432u
#define BNA_OFF 33898496u
#define BNB_OFF 33899008u
#define FK_OFF  33899520u
#define PT_OFF  33997824u

__device__ __forceinline__ u32 fkey(float f) {          // order-preserving
  u32 u = __float_as_uint(f);
  return (u & 0x80000000u) ? ~u : (u | 0x80000000u);
}
__device__ __forceinline__ float funkey(u32 k) {
  u32 u = (k & 0x80000000u) ? (k ^ 0x80000000u) : ~k;
  return __uint_as_float(u);
}

__device__ __forceinline__ i8 q8(float v) {
  v = fminf(fmaxf(v, -127.f), 127.f);
  return (i8)__float2int_rn(v);
}

__device__ __forceinline__ void gload_lds16(void* lds, const void* g) {
  __builtin_amdgcn_global_load_lds(
      (const __attribute__((address_space(1))) u32*)g,
      (__attribute__((address_space(3))) u32*)lds, 16, 0, 0);
}

// --------------------------- prep: |W| absmax partials ---------------------
__global__ void k_absmax(const float* __restrict__ W, float* __restrict__ parts) {
  const int i0 = ((int)blockIdx.x * 256 + (int)threadIdx.x) * 4;  // 336 blocks
  float m = 0.f;
#pragma unroll
  for (int j = 0; j < 4; ++j) m = fmaxf(m, fabsf(W[i0 + j]));
#pragma unroll
  for (int d = 1; d < 64; d <<= 1) m = fmaxf(m, __shfl_xor(m, d));
  if ((threadIdx.x & 63) == 0)
    parts[blockIdx.x * 4 + (threadIdx.x >> 6)] = m;
}

// --------------------------- fused prep ------------------------------------
// 256 threads; block-wide max of parts[1344] (used by bn & w paths).
__device__ __forceinline__ float reduce_parts(const float* __restrict__ parts,
                                              float* lds4) {
  float m = 0.f;
  for (int i = (int)threadIdx.x; i < 1344; i += 256) m = fmaxf(m, parts[i]);
#pragma unroll
  for (int d = 1; d < 64; d <<= 1) m = fmaxf(m, __shfl_xor(m, d));
  if (((int)threadIdx.x & 63) == 0) lds4[(int)threadIdx.x >> 6] = m;
  __syncthreads();
  return fmaxf(fmaxf(lds4[0], lds4[1]), fmaxf(lds4[2], lds4[3]));
}

__global__ void k_fused(const float* __restrict__ X, const float* __restrict__ W,
                        const float* __restrict__ g, const float* __restrict__ be,
                        const float* __restrict__ mn, const float* __restrict__ vr,
                        const float* __restrict__ parts, const int* __restrict__ olen,
                        i8* __restrict__ Xt, i8* __restrict__ Wp,
                        float* __restrict__ bnA, float* __restrict__ bnB,
                        u32* __restrict__ feat) {
  __shared__ float smem[C_SZ * 65];           // xt tile / reduce scratch
  const int tid = (int)threadIdx.x;
  const int bid = (int)blockIdx.x;

  if (bid < 4096) {
    // ---- X -> i8 transposed [b][t][ci], fixed scale SX ----
    const int b = bid >> 7;
    const int t0 = (bid & 127) * 64;
    // rows beyond L1+278 are never staged by any surviving conv block
    const int L1 = olen[b] - (KW - 1);
    if (t0 > L1 + 278) return;
    const float* Xb = X + (size_t)b * C_SZ * T_SZ;
    {
      const int cw = tid >> 4;                // 0..15
      const int ch = tid & 15;                // float4 chunk along t
#pragma unroll
      for (int it = 0; it < 8; ++it) {
        const int ci = it * 16 + cw;
        const f32x4 v = *(const f32x4*)&Xb[(size_t)ci * T_SZ + t0 + ch * 4];
        smem[ci * 65 + ch * 4 + 0] = v.x;
        smem[ci * 65 + ch * 4 + 1] = v.y;
        smem[ci * 65 + ch * 4 + 2] = v.z;
        smem[ci * 65 + ch * 4 + 3] = v.w;
      }
    }
    __syncthreads();
    const int t = tid >> 2;                   // 0..63
    const int q = tid & 3;                    // 32-ci quarter
    u32 dw[8];
#pragma unroll
    for (int d = 0; d < 8; ++d) {
      u32 w = 0;
#pragma unroll
      for (int jb = 0; jb < 4; ++jb) {
        const int j = d * 4 + jb;
        const float v = smem[(q * 32 + j) * 65 + t] * SX;
        w |= ((u32)(unsigned char)q8(v)) << (jb * 8);
      }
      dw[d] = w;
    }
    u32* dst = (u32*)(Xt + ((size_t)(b * T_SZ + t0 + t)) * C_SZ + q * 32);
    *(i32x4*)(dst + 0) = (i32x4){(int)dw[0], (int)dw[1], (int)dw[2], (int)dw[3]};
    *(i32x4*)(dst + 4) = (i32x4){(int)dw[4], (int)dw[5], (int)dw[6], (int)dw[7]};
  } else if (bid == 4096) {
    // ---- BN fold (+ dequant scale) and feat zeroing ----
    const float wmax = reduce_parts(parts, smem);
    if (tid < C_SZ) {
      const float sw = 127.f / wmax;
      const float invS = 1.f / (SX * sw);
      float inv = rsqrtf(vr[tid] + 1e-5f);
      float a = g[tid] * inv;
      bnA[tid] = a * invS;
      bnB[tid] = be[tid] - a * mn[tid];
    }
    for (int i = tid; i < B_SZ * FEAT; i += 256) feat[i] = 0u;
  } else {
    // ---- W -> i8 wave panels ----
    // Wp byte idx = (((k*2+wr)*8 + f)*64 + lane)*16 + e   (f = ks*4 + m)
    // maps W[co = wr*64+m*16+(lane&15)][ci = ks*64+(lane>>4)*16+e][k]
    const float wmax = reduce_parts(parts, smem);
    const float sw = 127.f / wmax;
    const int i = (bid - 4097) * 256 + tid;   // 1344 blocks -> 344064
    const int e = i & 15;
    const int lane = (i >> 4) & 63;
    const int f = (i >> 10) & 7;
    const int wr = (i >> 13) & 1;
    const int k = i >> 14;
    const int m = f & 3, ks = f >> 2;
    const int co = wr * 64 + m * 16 + (lane & 15);
    const int ci = ks * 64 + (lane >> 4) * 16 + e;
    Wp[i] = q8(W[(co * C_SZ + ci) * KW + k] * sw);
  }
}

// --------------------------- conv + SPP-max (int domain) -------------------
// Block 256 thr (4 waves 2x2), tile 128co x 256t; wave 64co x 128t.
// Early-exit: t0 >= L1 -> entire tile dead (all windows in [0,L1)).
// Fully-unrolled barrier-free K-loop; av in registers (L2 panels, ks-half
// rotation); bv from granule-XOR swizzled i8 Xs (row = 128B = 8 granules).
// Epilogue: window max in raw i32 (BN+leaky monotone, bnA>0); 4 windows
// reduced, w0/w3 derived at combine.
__global__ __launch_bounds__(256, 2)
void k_conv(const i8* __restrict__ Xt, const i8* __restrict__ Wp,
            const float* __restrict__ bnA, const float* __restrict__ bnB,
            const int* __restrict__ olen, u32* __restrict__ feat) {
  __shared__ __align__(16) i8 Xs[280 * C_SZ];   // 35840 B
  __shared__ int parti[2][4][C_SZ];             //  4096 B (total 39936)

  const int tid = (int)threadIdx.x;
  const int wid = tid >> 6, lane = tid & 63;
  const int wr = wid >> 1, wc = wid & 1;
  const int l4 = lane & 15, lh = lane >> 4;
  const int b = (int)blockIdx.y;
  const int t0 = (int)blockIdx.x * 256;

  const int len = olen[b];
  const int L1 = len - (KW - 1);
  const int L2 = len - 2 * (KW - 1);
  if (t0 >= L1) return;                       // dead tile: no window reaches it

  // ---- prefetch W panels for tap 0 ----
  const i8* wbase = Wp + ((size_t)wr << 13) + (lane << 4);
  i32x4 av[2][4];
#pragma unroll
  for (int f = 0; f < 8; ++f)
    av[f >> 2][f & 3] = *(const i32x4*)&wbase[f << 10];

  // ---- stage Xs rows 0..279 (8 rows = 1024B per wave-instruction) ----
  // LDS[row][g] = global[row][g ^ (row&7)] (16B granules)
  {
    const i8* xb = Xt + (size_t)b * T_SZ * C_SZ;
    for (int i = wid; i < 35; i += 4) {
      int trow = t0 + i * 8 + (lane >> 3);
      trow = trow < T_SZ ? trow : (T_SZ - 1);
      const i8* src = xb + (size_t)trow * C_SZ + (((lane & 7) ^ (trow & 7)) << 4);
      gload_lds16(&Xs[i * 1024], src);
    }
  }
  __syncthreads();                            // the only barrier before epilogue

  i32x4 acc[4][8];
#pragma unroll
  for (int m = 0; m < 4; ++m)
#pragma unroll
    for (int n = 0; n < 8; ++n) acc[m][n] = (i32x4){0, 0, 0, 0};

  const int rowc = wc * 128 + l4;
#pragma unroll
  for (int k = 0; k < KW; ++k) {              // full unroll: static Wp offsets
    const int kn = (k + 1 < KW) ? (k + 1) : k;
    const int rowb = rowc + k;
    const i8* wbn = wbase + ((size_t)kn << 14);
#pragma unroll
    for (int ks = 0; ks < 2; ++ks) {
      const int gran = ((ks << 2) + lh) ^ (rowb & 7);
      const i8* xp = &Xs[(rowb << 7) + (gran << 4)];
      i32x4 bv[8];
#pragma unroll
      for (int n = 0; n < 8; ++n)
        bv[n] = *(const i32x4*)&xp[n << 11];  // n*16 rows * 128B
      __builtin_amdgcn_s_setprio(1);
#pragma unroll
      for (int m = 0; m < 4; ++m)
#pragma unroll
        for (int n = 0; n < 8; ++n)
          acc[m][n] = __builtin_amdgcn_mfma_i32_16x16x64_i8(
              av[ks][m], bv[n], acc[m][n], 0, 0, 0);
      __builtin_amdgcn_s_setprio(0);
      // prefetch this ks-half of next tap (distance ~32 MFMA min)
#pragma unroll
      for (int m = 0; m < 4; ++m)
        av[ks][m] = *(const i32x4*)&wbn[((ks << 2) + m) << 10];
    }
  }

  // ---- epilogue: 4-window ragged max in i32 domain ----
  int wlo[4], whi[4];
  wlo[0] = 0;       whi[0] = (L1 + 1) >> 1;   // w1
  wlo[1] = L1 >> 1; whi[1] = L1;              // w2
  wlo[2] = 0;       whi[2] = (L2 + 1) >> 1;   // w4
  wlo[3] = L2 >> 1; whi[3] = L2;              // w5

  int tg[8];
#pragma unroll
  for (int n = 0; n < 8; ++n) tg[n] = t0 + wc * 128 + n * 16 + l4;

#pragma unroll
  for (int w = 0; w < 4; ++w) {
    bool pr[8];
#pragma unroll
    for (int n = 0; n < 8; ++n) pr[n] = (tg[n] >= wlo[w]) & (tg[n] < whi[w]);
#pragma unroll
    for (int m = 0; m < 4; ++m)
#pragma unroll
      for (int r = 0; r < 4; ++r) {
        int mx = IMIN;
#pragma unroll
        for (int n = 0; n < 8; ++n)
          mx = max(mx, pr[n] ? acc[m][n][r] : IMIN);
#pragma unroll
        for (int d = 1; d < 16; d <<= 1) mx = max(mx, __shfl_xor(mx, d));
        if (l4 == 0) parti[wc][w][wr * 64 + m * 16 + lh * 4 + r] = mx;
      }
  }
  __syncthreads();
  // ---- combine: BN + leaky + fkey on 6x128 reduced values ----
  if (tid < C_SZ) {
    const int c = tid;
    const int v1 = max(parti[0][0][c], parti[1][0][c]);
    const int v2 = max(parti[0][1][c], parti[1][1][c]);
    const int v4 = max(parti[0][2][c], parti[1][2][c]);
    const int v5 = max(parti[0][3][c], parti[1][3][c]);
    const int v0 = max(v1, v2);
    const int v3 = max(v4, v5);
    const float a = bnA[c], bb = bnB[c];
    u32* fb_ = feat + b * FEAT;
    float h;
    h = a * (float)v0 + bb; h = h > 0.f ? h : 0.01f * h;
    atomicMax(&fb_[c], fkey(h));
    h = a * (float)v1 + bb; h = h > 0.f ? h : 0.01f * h;
    atomicMax(&fb_[128 + 2 * c], fkey(h));
    h = a * (float)v2 + bb; h = h > 0.f ? h : 0.01f * h;
    atomicMax(&fb_[129 + 2 * c], fkey(h));
    h = a * (float)v3 + bb; h = h > 0.f ? h : 0.01f * h;
    atomicMax(&fb_[384 + c], fkey(h));
    h = a * (float)v4 + bb; h = h > 0.f ? h : 0.01f * h;
    atomicMax(&fb_[512 + 2 * c], fkey(h));
    h = a * (float)v5 + bb; h = h > 0.f ? h : 0.01f * h;
    atomicMax(&fb_[513 + 2 * c], fkey(h));
  }
}

// --------------------------- FC head ---------------------------------------
__global__ void k_fc(const u32* __restrict__ feat, const float* __restrict__ fw,
                     const float* __restrict__ fb, float* __restrict__ out) {
  const int bj = (int)blockIdx.x;             // 0..63
  const int b = bj >> 1, j = bj & 1;
  const int lane = (int)threadIdx.x;          // 64
  float s = 0.f;
  for (int i = lane; i < FEAT; i += 64)
    s += funkey(feat[b * FEAT + i]) * fw[j * FEAT + i];
#pragma unroll
  for (int d = 1; d < 64; d <<= 1) s += __shfl_xor(s, d);
  if (lane == 0) out[b * 2 + j] = s + fb[j];
}

// ---------------------------------------------------------------------------
extern "C" void kernel_launch(void* const* d_in, const int* in_sizes, int n_in,
                              void* d_out, int out_size, void* d_ws, size_t ws_size,
                              hipStream_t stream) {
  (void)in_sizes; (void)n_in; (void)out_size; (void)ws_size;
  const float* x     = (const float*)d_in[0];
  const int*   olen  = (const int*)d_in[1];
  const float* w     = (const float*)d_in[2];
  const float* gamma = (const float*)d_in[3];
  const float* beta  = (const float*)d_in[4];
  const float* mean  = (const float*)d_in[5];
  const float* var   = (const float*)d_in[6];
  const float* fw    = (const float*)d_in[7];
  const float* fb    = (const float*)d_in[8];
  float* out = (float*)d_out;

  char* ws = (char*)d_ws;
  i8*  Xt    = (i8*)(ws + XT_OFF);
  i8*  Wp    = (i8*)(ws + WP_OFF);
  float* bnA  = (float*)(ws + BNA_OFF);
  float* bnB  = (float*)(ws + BNB_OFF);
  u32* feat  = (u32*)(ws + FK_OFF);
  float* parts = (float*)(ws + PT_OFF);

  k_absmax<<<336, 256, 0, stream>>>(w, parts);
  k_fused<<<4097 + 1344, 256, 0, stream>>>(x, w, gamma, beta, mean, var, parts,
                                           olen, Xt, Wp, bnA, bnB, feat);
  k_conv<<<dim3(T_SZ / 256, B_SZ), 256, 0, stream>>>(Xt, Wp, bnA, bnB, olen, feat);
  k_fc<<<64, 64, 0, stream>>>(feat, fw, fb, out);
}